// Round 7
// baseline (1798.258 us; speedup 1.0000x reference)
//
#include <hip/hip_runtime.h>
#include <hip/hip_bf16.h>

#define B_    2
#define L_    2048
#define D_    4096
#define F_    11008
#define M_TOK (B_ * L_)          // 4096 tokens
#define BM    256
#define M_ALLOC (M_TOK + BM)     // 4352: vision [0,nv), 256-gap, language at top
#define NTM   (M_ALLOC / BM)     // 17 M-tiles
#define NT_GU (D_ / 64)          // 64 K-tiles for gate/up
#define NT_DN (F_ / 64)          // 172 K-tiles for down
#define NTILE_F (F_ / 128)       // 86 N-tiles for fused gate+up (128 cols each)
#define SPLITK_DN 4
#define LDS_GU 131072            // A 2x32KB + Bg 2x16KB + Bu 2x16KB
#define LDS_DN 131072            // A 2x32KB + B 2x32KB

typedef __attribute__((ext_vector_type(8))) __bf16 bf16x8;
typedef __attribute__((ext_vector_type(4))) float  f32x4;
typedef unsigned short ushort_t;
typedef unsigned int   uint_t;

// ---------------------------------------------------------------- primitives

__device__ __forceinline__ void gload_lds16(const void* g, void* l) {
  __builtin_amdgcn_global_load_lds(
      (const __attribute__((address_space(1))) void*)g,
      (__attribute__((address_space(3))) void*)l, 16, 0, 0);
}

#define PH_BAR()  { __builtin_amdgcn_sched_barrier(0); __builtin_amdgcn_s_barrier(); __builtin_amdgcn_sched_barrier(0); }
#define VM0()     { asm volatile("s_waitcnt vmcnt(0)" ::: "memory"); __builtin_amdgcn_sched_barrier(0); }

__device__ __forceinline__ ushort_t f2bf(float v) {
  union { __hip_bfloat16 h; ushort_t u; } cv;
  cv.h = __float2bfloat16(v);
  return cv.u;
}

// bijective XCD swizzle (m204)
__device__ __forceinline__ int xcd_swz(int orig, int nwg) {
  const int q = nwg >> 3, r = nwg & 7, xcd = orig & 7;
  return (xcd < r ? xcd * (q + 1) : r * (q + 1) + (xcd - r) * q) + (orig >> 3);
}

// stage one 128x64 bf16 half-tile (8192 elems / 16 KB), inverse-swizzled
// source -> linear LDS. Swizzle (involution): byte ^= (row&7)<<4.
__device__ __forceinline__ void stage_half(const __hip_bfloat16* __restrict__ src, int ldE,
                                           __bf16* ldsb, int w, int lane) {
#pragma unroll
  for (int j = 0; j < 2; ++j) {
    const int ch  = (w * 2 + j) * 64 + lane;   // 16B chunk id, 0..1023
    const int row = ch >> 3;                   // 0..127
    const int cc  = (ch & 7) ^ (row & 7);      // pre-swizzled col chunk
    gload_lds16(src + (size_t)(row * ldE + cc * 8), ldsb + (w * 2 + j) * 512);
  }
}

// swizzled ds_read_b128 of one MFMA fragment from a [rows][64] bf16 region
__device__ __forceinline__ bf16x8 ldfrag(const __bf16* region, int row, int koffb) {
  const int off = ((row << 7) + koffb) ^ ((row & 7) << 4);
  return *(const bf16x8*)((const char*)region + off);
}

// ---------------------------------------------------------------- preprocessing

__global__ void init_kernel(int* counters, int* slot2tok) {
  int i = blockIdx.x * 256 + threadIdx.x;
  if (i < 2) counters[i] = 0;
  if (i < M_ALLOC) slot2tok[i] = -1;
}

__global__ void assign_kernel(const int* __restrict__ tt, int* counters,
                              int* __restrict__ slot2tok) {
  int t = blockIdx.x * 256 + threadIdx.x;
  if (t >= M_TOK) return;
  int l = t & (L_ - 1);
  bool isv = (tt[t] == 1) && (l < L_ - 1) && (tt[t + 1] == 1);
  int slot;
  if (isv) slot = atomicAdd(&counters[0], 1);
  else     slot = M_ALLOC - 1 - atomicAdd(&counters[1], 1);
  slot2tok[slot] = t;
}

__global__ void gather_cvt(const float* __restrict__ x, const int* __restrict__ slot2tok,
                           __hip_bfloat16* __restrict__ xg) {
  const int s = blockIdx.x;
  const int t = slot2tok[s];
  __hip_bfloat16* dst = xg + (size_t)s * D_ + threadIdx.x * 16;
  union { ushort_t h[8]; uint4 v; } p0, p1;
  if (t >= 0) {
    const float4* s4 = (const float4*)(x + (size_t)t * D_ + threadIdx.x * 16);
    float4 a = s4[0], b = s4[1], c = s4[2], d = s4[3];
    float vals[16] = {a.x,a.y,a.z,a.w,b.x,b.y,b.z,b.w,c.x,c.y,c.z,c.w,d.x,d.y,d.z,d.w};
#pragma unroll
    for (int i = 0; i < 8; ++i) p0.h[i] = f2bf(vals[i]);
#pragma unroll
    for (int i = 0; i < 8; ++i) p1.h[i] = f2bf(vals[8 + i]);
  } else {
    p0.v = make_uint4(0, 0, 0, 0);
    p1.v = make_uint4(0, 0, 0, 0);
  }
  *(uint4*)dst = p0.v;
  *(uint4*)(dst + 8) = p1.v;
}

// f32 [R][C] -> bf16 [C][R]; coalesced reads, 64B/lane contiguous writes
__global__ __launch_bounds__(128) void transpose_cvt64(const float* __restrict__ in,
                                                       __hip_bfloat16* __restrict__ out,
                                                       int R, int C) {
  const int c  = threadIdx.x & 63;
  const int rc = threadIdx.x >> 6;
  const int c0 = blockIdx.x * 64;
  const int r0 = blockIdx.y * 64 + rc * 32;
  const float* ip = in + (size_t)r0 * C + c0 + c;
  uint_t pk[16];
#pragma unroll
  for (int j = 0; j < 16; ++j) {
    float v0 = ip[(size_t)(2 * j) * C];
    float v1 = ip[(size_t)(2 * j + 1) * C];
    pk[j] = (uint_t)f2bf(v0) | ((uint_t)f2bf(v1) << 16);
  }
  uint4* op = (uint4*)(out + (size_t)(c0 + c) * R + r0);
#pragma unroll
  for (int k = 0; k < 4; ++k)
    op[k] = make_uint4(pk[4 * k], pk[4 * k + 1], pk[4 * k + 2], pk[4 * k + 3]);
}

__global__ void sentinel_kernel(float* out, int n) {
  int i = blockIdx.x * 256 + threadIdx.x;
  if (i < n) out[i] = 1e30f;
}

// ---------------------------------------------------------------- GEMM 1: fused gate+up+silu
// Tile 256(M) x 128(F-cols); 8 waves 4Mx2N, per-wave 64x64 dual acc (gate,up).
// Single-barrier free-running K-loop: per tile {stage t+1 -> alt buffers;
// sched fence; 24 ds_read + 64 MFMA compiler-interleaved; vmcnt(0); barrier}.
// Hazards: reads hit buf[cur], stages hit buf[nxt] (disjoint); stages of t+2
// gated by the tile-t barrier; all tile-t reads lgkm-complete before barrier.
// LDS map (elems): A dbuf 0 / 16384 (each 256x64); Bg dbuf 32768 / 40960
// (each 128x64 = 8192 elems); Bu dbuf 49152 / 57344.  [round-6 bug: Bg/Bu
// stride was 4096 -> stage_half(8192 elems) clobbered both buffers]
__global__ __launch_bounds__(512, 2) void gemm256_gateup_fused(
    const __hip_bfloat16* __restrict__ Xg,
    const __hip_bfloat16* __restrict__ WgTv, const __hip_bfloat16* __restrict__ WuTv,
    const __hip_bfloat16* __restrict__ WgTl, const __hip_bfloat16* __restrict__ WuTl,
    __hip_bfloat16* __restrict__ H, const int* __restrict__ counters) {
  extern __shared__ __bf16 smem[];
  const int tid = threadIdx.x, lane = tid & 63, w = tid >> 6;
  const int wm = w >> 1, wn = w & 1;
  const int l15 = lane & 15, l4 = lane >> 4;

  const int wg = xcd_swz(blockIdx.x, gridDim.x);
  const int mt = wg % NTM, ntile = wg / NTM;   // N-major: consecutive wg share B-panel
  const int row0 = mt * BM;
  const int ncol0 = ntile * 128;
  const int nv = counters[0];
  const bool isv = row0 < nv;
  const __hip_bfloat16* Ag   = Xg + (size_t)row0 * D_;
  const __hip_bfloat16* Bg_g = (isv ? WgTv : WgTl) + (size_t)ncol0 * D_;
  const __hip_bfloat16* Bu_g = (isv ? WuTv : WuTl) + (size_t)ncol0 * D_;

  f32x4 accg[4][4] = {};
  f32x4 accu[4][4] = {};
  const int nt = NT_GU;

  stage_half(Ag,             D_, smem,         w, lane);
  stage_half(Ag + 128 * D_,  D_, smem + 8192,  w, lane);
  stage_half(Bg_g,           D_, smem + 32768, w, lane);
  stage_half(Bu_g,           D_, smem + 49152, w, lane);
  VM0(); PH_BAR();

  for (int t = 0; t < nt; ++t) {
    const int cur = t & 1;
    const __bf16* At  = smem + cur * 16384;
    const __bf16* Bgt = smem + 32768 + cur * 8192;
    const __bf16* But = smem + 49152 + cur * 8192;
    if (t + 1 < nt) {
      __bf16* nA  = smem + (cur ^ 1) * 16384;
      __bf16* nBg = smem + 32768 + (cur ^ 1) * 8192;
      __bf16* nBu = smem + 49152 + (cur ^ 1) * 8192;
      stage_half(Ag + (t + 1) * 64,            D_, nA,        w, lane);
      stage_half(Ag + (t + 1) * 64 + 128 * D_, D_, nA + 8192, w, lane);
      stage_half(Bg_g + (t + 1) * 64,          D_, nBg,       w, lane);
      stage_half(Bu_g + (t + 1) * 64,          D_, nBu,       w, lane);
    }
    __builtin_amdgcn_sched_barrier(0);   // stages stay at tile top

    bf16x8 af[4][2], bg[4][2], bu[4][2];
#pragma unroll
    for (int m = 0; m < 4; ++m)
#pragma unroll
      for (int ks = 0; ks < 2; ++ks)
        af[m][ks] = ldfrag(At, wm * 64 + m * 16 + l15, ks * 64 + l4 * 16);
#pragma unroll
    for (int n = 0; n < 4; ++n)
#pragma unroll
      for (int ks = 0; ks < 2; ++ks)
        bg[n][ks] = ldfrag(Bgt, wn * 64 + n * 16 + l15, ks * 64 + l4 * 16);
#pragma unroll
    for (int m = 0; m < 4; ++m)
#pragma unroll
      for (int n = 0; n < 4; ++n)
#pragma unroll
        for (int ks = 0; ks < 2; ++ks)
          accg[m][n] = __builtin_amdgcn_mfma_f32_16x16x32_bf16(
              af[m][ks], bg[n][ks], accg[m][n], 0, 0, 0);
#pragma unroll
    for (int n = 0; n < 4; ++n)
#pragma unroll
      for (int ks = 0; ks < 2; ++ks)
        bu[n][ks] = ldfrag(But, wn * 64 + n * 16 + l15, ks * 64 + l4 * 16);
#pragma unroll
    for (int m = 0; m < 4; ++m)
#pragma unroll
      for (int n = 0; n < 4; ++n)
#pragma unroll
        for (int ks = 0; ks < 2; ++ks)
          accu[m][n] = __builtin_amdgcn_mfma_f32_16x16x32_bf16(
              af[m][ks], bu[n][ks], accu[m][n], 0, 0, 0);

    if (t + 1 < nt) VM0();
    PH_BAR();
  }

  // epilogue: H = silu(g) * u, bf16
#pragma unroll
  for (int m = 0; m < 4; ++m) {
    const int grow = row0 + wm * 64 + m * 16 + l4 * 4;
#pragma unroll
    for (int rr = 0; rr < 4; ++rr) {
      __hip_bfloat16* orow = H + (size_t)(grow + rr) * F_ + ncol0 + wn * 64 + l15;
#pragma unroll
      for (int n = 0; n < 4; ++n) {
        const float g = accg[m][n][rr];
        const float u = accu[m][n][rr];
        orow[n * 16] = __float2bfloat16(g / (1.0f + __expf(-g)) * u);
      }
    }
  }
}

// ---------------------------------------------------------------- GEMM 2: down + scatter
// 256x256 tile, 8 waves 2Mx4N, per-wave 128x64. Same single-barrier K-loop.
// LDS map (elems): A dbuf 0 / 16384; B dbuf 32768 / 49152 (each 256x64).
__global__ __launch_bounds__(512, 2) void gemm256_down(
    const __hip_bfloat16* __restrict__ H,
    const __hip_bfloat16* __restrict__ WdTv, const __hip_bfloat16* __restrict__ WdTl,
    float* __restrict__ out, const int* __restrict__ counters,
    const int* __restrict__ slot2tok) {
  extern __shared__ __bf16 smem[];
  const int tid = threadIdx.x, lane = tid & 63, w = tid >> 6;
  const int wm = w >> 2, wn = w & 3;
  const int l15 = lane & 15, l4 = lane >> 4;

  const int wg = xcd_swz(blockIdx.x, gridDim.x);
  const int mt = wg % NTM, ntt = wg / NTM;   // N-major
  const int z  = blockIdx.y;                 // split-K
  const int row0 = mt * BM;
  const int ncol0 = ntt * 256;
  const int ntz = NT_DN / SPLITK_DN;         // 43
  const int nv = counters[0];
  const __hip_bfloat16* Bsrc = (row0 < nv) ? WdTv : WdTl;
  const __hip_bfloat16* Ag = H + (size_t)row0 * F_ + z * ntz * 64;
  const __hip_bfloat16* Bg = Bsrc + (size_t)ncol0 * F_ + z * ntz * 64;

  f32x4 acc[8][4] = {};
  const int nt = ntz;

  stage_half(Ag,             F_, smem,         w, lane);
  stage_half(Ag + 128 * F_,  F_, smem + 8192,  w, lane);
  stage_half(Bg,             F_, smem + 32768, w, lane);
  stage_half(Bg + 128 * F_,  F_, smem + 40960, w, lane);
  VM0(); PH_BAR();

  for (int t = 0; t < nt; ++t) {
    const int cur = t & 1;
    const __bf16* At = smem + cur * 16384;
    const __bf16* Bt = smem + 32768 + cur * 16384;
    if (t + 1 < nt) {
      __bf16* nA = smem + (cur ^ 1) * 16384;
      __bf16* nB = smem + 32768 + (cur ^ 1) * 16384;
      stage_half(Ag + (t + 1) * 64,            F_, nA,        w, lane);
      stage_half(Ag + (t + 1) * 64 + 128 * F_, F_, nA + 8192, w, lane);
      stage_half(Bg + (t + 1) * 64,            F_, nB,        w, lane);
      stage_half(Bg + (t + 1) * 64 + 128 * F_, F_, nB + 8192, w, lane);
    }
    __builtin_amdgcn_sched_barrier(0);

    bf16x8 af[8][2], bf_[4][2];
#pragma unroll
    for (int m = 0; m < 8; ++m)
#pragma unroll
      for (int ks = 0; ks < 2; ++ks)
        af[m][ks] = ldfrag(At, wm * 128 + m * 16 + l15, ks * 64 + l4 * 16);
#pragma unroll
    for (int n = 0; n < 4; ++n)
#pragma unroll
      for (int ks = 0; ks < 2; ++ks)
        bf_[n][ks] = ldfrag(Bt, wn * 64 + n * 16 + l15, ks * 64 + l4 * 16);
#pragma unroll
    for (int m = 0; m < 8; ++m)
#pragma unroll
      for (int n = 0; n < 4; ++n)
#pragma unroll
        for (int ks = 0; ks < 2; ++ks)
          acc[m][n] = __builtin_amdgcn_mfma_f32_16x16x32_bf16(
              af[m][ks], bf_[n][ks], acc[m][n], 0, 0, 0);

    if (t + 1 < nt) VM0();
    PH_BAR();
  }

#pragma unroll
  for (int m = 0; m < 8; ++m) {
    const int slot = row0 + wm * 128 + m * 16 + l4 * 4;
#pragma unroll
    for (int rr = 0; rr < 4; ++rr) {
      const int tok = slot2tok[slot + rr];
      if (tok < 0) continue;
      float* orow = out + (size_t)tok * D_ + ncol0 + wn * 64 + l15;
#pragma unroll
      for (int n = 0; n < 4; ++n)
        atomicAdd(&orow[n * 16], acc[m][n][rr]);
    }
  }
}

// ---------------------------------------------------------------- host

extern "C" void kernel_launch(void* const* d_in, const int* in_sizes, int n_in,
                              void* d_out, int out_size, void* d_ws, size_t ws_size,
                              hipStream_t stream) {
  const float* x   = (const float*)d_in[0];
  const int*   tt  = (const int*)d_in[1];
  const float* wgv = (const float*)d_in[2];
  const float* wuv = (const float*)d_in[3];
  const float* wdv = (const float*)d_in[4];
  const float* wgl = (const float*)d_in[5];
  const float* wul = (const float*)d_in[6];
  const float* wdl = (const float*)d_in[7];
  float* out = (float*)d_out;

  size_t off = 0;
  auto nalign = [](size_t v) { return (v + 255) & ~(size_t)255; };
  const size_t o_cnt = off; off += nalign(2 * sizeof(int));
  const size_t o_s2t = off; off += nalign((size_t)M_ALLOC * sizeof(int));
  const size_t o_xg  = off; off += nalign((size_t)M_ALLOC * D_ * 2);
  const size_t o_h   = off; off += nalign((size_t)M_ALLOC * F_ * 2);
  const size_t wbytes = nalign((size_t)D_ * F_ * 2);
  const size_t o_wgv = off; off += wbytes;   // later reused for WdTv
  const size_t o_wuv = off; off += wbytes;   // later reused for WdTl
  const size_t o_wgl = off; off += wbytes;
  const size_t o_wul = off; off += wbytes;

  if (ws_size < off) {
    sentinel_kernel<<<(out_size + 255) / 256, 256, 0, stream>>>(out, out_size);
    return;
  }

  char* ws = (char*)d_ws;
  int* counters = (int*)(ws + o_cnt);
  int* slot2tok = (int*)(ws + o_s2t);
  __hip_bfloat16* Xg  = (__hip_bfloat16*)(ws + o_xg);
  __hip_bfloat16* H   = (__hip_bfloat16*)(ws + o_h);
  __hip_bfloat16* WgTv = (__hip_bfloat16*)(ws + o_wgv);
  __hip_bfloat16* WuTv = (__hip_bfloat16*)(ws + o_wuv);
  __hip_bfloat16* WgTl = (__hip_bfloat16*)(ws + o_wgl);
  __hip_bfloat16* WuTl = (__hip_bfloat16*)(ws + o_wul);
  __hip_bfloat16* WdTv = WgTv;  // reuse after gateup consumed gate/up weights
  __hip_bfloat16* WdTl = WuTv;

  hipFuncSetAttribute((const void*)gemm256_gateup_fused,
                      hipFuncAttributeMaxDynamicSharedMemorySize, LDS_GU);
  hipFuncSetAttribute((const void*)gemm256_down,
                      hipFuncAttributeMaxDynamicSharedMemorySize, LDS_DN);

  hipMemsetAsync(out, 0, (size_t)out_size * sizeof(float), stream);

  init_kernel<<<(M_ALLOC + 255) / 256, 256, 0, stream>>>(counters, slot2tok);
  assign_kernel<<<(M_TOK + 255) / 256, 256, 0, stream>>>(tt, counters, slot2tok);
  gather_cvt<<<M_ALLOC, 256, 0, stream>>>(x, slot2tok, Xg);

  dim3 tb(128);
  dim3 tg_gu(F_ / 64, D_ / 64);   // in [D][F] -> out [F][D]
  transpose_cvt64<<<tg_gu, tb, 0, stream>>>(wgv, WgTv, D_, F_);
  transpose_cvt64<<<tg_gu, tb, 0, stream>>>(wuv, WuTv, D_, F_);
  transpose_cvt64<<<tg_gu, tb, 0, stream>>>(wgl, WgTl, D_, F_);
  transpose_cvt64<<<tg_gu, tb, 0, stream>>>(wul, WuTl, D_, F_);

  gemm256_gateup_fused<<<dim3(NTM * NTILE_F), 512, LDS_GU, stream>>>(
      Xg, WgTv, WuTv, WgTl, WuTl, H, counters);

  dim3 tg_dn(D_ / 64, F_ / 64);   // in [F][D] -> out [D][F]
  transpose_cvt64<<<tg_dn, tb, 0, stream>>>(wdv, WdTv, F_, D_);
  transpose_cvt64<<<tg_dn, tb, 0, stream>>>(wdl, WdTl, F_, D_);

  gemm256_down<<<dim3(NTM * (D_ / 256), SPLITK_DN), 512, LDS_DN, stream>>>(
      H, WdTv, WdTl, out, counters, slot2tok);
}